// Round 10
// baseline (694.513 us; speedup 1.0000x reference)
//
#include <hip/hip_runtime.h>

// EPN_flax, round 10: hot loop identical to round 9 (K=16 f16 MFMA E-term with
// C-init = Pi+Qj / Pj+Qi; K=32 f16 MFMA layer 2 with C-init = b1/16, k-permuted
// W1 frags -> register-only handoff; 1/16 pre-scale; b2 cancels). New:
//  - grid 2048 (8 blocks/CU = full 32 waves/CU co-residency), 2 j-tiles/block.
//  - proj kernels eliminated: Pb/Qb = q-independent base (all 3 t, setup once);
//    q enters as rank-1 update during staging, qa = q + sum of prior delta
//    buffers; mains atomically accumulate into zeroed D_t (not qout).
//  - 5 launches total: setup, 3 chained mains, final qout = q + D0+D1+D2.

constexpr int Nn = 1024;

typedef _Float16 half4 __attribute__((ext_vector_type(4)));
typedef _Float16 half8 __attribute__((ext_vector_type(8)));
typedef __fp16   fp16x2 __attribute__((ext_vector_type(2)));
typedef float    f32x4 __attribute__((ext_vector_type(4)));
typedef unsigned int uint2v __attribute__((ext_vector_type(2)));
typedef unsigned int uint4v __attribute__((ext_vector_type(4)));

#define MFMAH32(A, B, C) __builtin_amdgcn_mfma_f32_16x16x32_f16(A, B, C, 0, 0, 0)

#if __has_builtin(__builtin_amdgcn_mfma_f32_16x16x16f16)
__device__ inline f32x4 mfma16(half4 a, half4 b, f32x4 c) {
    return __builtin_amdgcn_mfma_f32_16x16x16f16(a, b, c, 0, 0, 0);
}
#else
__device__ inline f32x4 mfma16(half4 a, half4 b, f32x4 c) {
    half8 a8 = {a[0], a[1], a[2], a[3], (_Float16)0, (_Float16)0, (_Float16)0, (_Float16)0};
    half8 b8 = {b[0], b[1], b[2], b[3], (_Float16)0, (_Float16)0, (_Float16)0, (_Float16)0};
    return MFMAH32(a8, b8, c);
}
#endif

__device__ inline unsigned int pkrtz(float a, float b) {
    fp16x2 r = __builtin_amdgcn_cvt_pkrtz(a, b);
    return __builtin_bit_cast(unsigned int, r);
}
__device__ inline f32x4 max0(f32x4 a) {
    f32x4 z = {0.f, 0.f, 0.f, 0.f};
    return __builtin_elementwise_max(a, z);
}

// ---- setup: Pb/Qb bases (3 t), weight frags, scaled vectors, zero D ----
__global__ __launch_bounds__(256) void epn_setup_kernel(
    const float* __restrict__ W0,   // [3][80][64]
    const float* __restrict__ W1,   // [3][64][64]
    const float* __restrict__ b0,   // [3][64]
    const float* __restrict__ b1,   // [3][64]
    const float* __restrict__ W2,   // [3][64]
    const float* __restrict__ h,    // [1024][31]
    uint2v* __restrict__ fw0e,      // [3][4][64]
    uint4*  __restrict__ fw1,       // [3][8][64]
    float*  __restrict__ b1s,       // [3][64] = b1/16
    float*  __restrict__ w2s,       // [3][64] = 16*W2
    float*  __restrict__ w31s,      // [3][64] = W0[31]/16
    float*  __restrict__ w63s,      // [3][64] = W0[63]/16
    float*  __restrict__ Pb,        // [3][1024][64]
    float*  __restrict__ Qb,        // [3][1024][64]
    float*  __restrict__ D)         // [3][1024] zeroed
{
    const int b = blockIdx.x, tid = threadIdx.x;
    if (b < 768) {                  // q-independent P/Q bases: ts = b>>8, 4 atoms/block
        const int ts = b >> 8, base = (b & 255) * 4;
        __shared__ float sa[4][32];
        if (tid < 128) {
            int la = tid >> 5, c = tid & 31;
            sa[la][c] = (c < 31) ? h[(base + la) * 31 + c] : 0.f;
        }
        __syncthreads();
        const int la = tid >> 6, m = tid & 63, atom = base + la;
        const float* W0t = W0 + ts * 80 * 64;
        float accP = b0[ts * 64 + m], accQ = 0.f;
        #pragma unroll
        for (int c = 0; c < 31; ++c) {
            float av = sa[la][c];
            accP = fmaf(av, W0t[c * 64 + m], accP);
            accQ = fmaf(av, W0t[(32 + c) * 64 + m], accQ);
        }
        Pb[((size_t)ts * Nn + atom) * 64 + m] = accP * 0.0625f;
        Qb[((size_t)ts * Nn + atom) * 64 + m] = accQ * 0.0625f;
    } else {
        const int idx = (b - 768) * 256 + tid;
        if (idx < 768) {                              // fw0e: (ts, t, lane)
            int lane = idx & 63, t = (idx >> 6) & 3, ts = idx >> 8;
            int nl = lane & 15, qd = lane >> 4;
            float v[4];
            #pragma unroll
            for (int j = 0; j < 4; ++j)
                v[j] = W0[ts * 80 * 64 + (64 + qd * 4 + j) * 64 + t * 16 + nl] * 0.0625f;
            uint2v p = {pkrtz(v[0], v[1]), pkrtz(v[2], v[3])};
            fw0e[idx] = p;
        } else if (idx < 2304) {                      // fw1: (ts, sp, t2, lane)
            int i2 = idx - 768;
            int lane = i2 & 63, t2 = (i2 >> 6) & 3, sp = (i2 >> 8) & 1, ts = i2 >> 9;
            int nl = lane & 15, qd = lane >> 4;
            float v[8];
            #pragma unroll
            for (int j = 0; j < 8; ++j) {
                int k = (2 * (j >> 2) + sp) * 16 + qd * 4 + (j & 3);   // sigma-permuted
                v[j] = W1[ts * 64 * 64 + k * 64 + t2 * 16 + nl];
            }
            uint4 p;
            p.x = pkrtz(v[0], v[1]); p.y = pkrtz(v[2], v[3]);
            p.z = pkrtz(v[4], v[5]); p.w = pkrtz(v[6], v[7]);
            fw1[(ts * 8 + sp * 4 + t2) * 64 + lane] = p;
        } else if (idx < 2496) {                      // b1s / w2s
            int i2 = idx - 2304;
            b1s[i2] = b1[i2] * 0.0625f;
            w2s[i2] = W2[i2] * 16.f;
        } else if (idx < 2688) {                      // w31s / w63s
            int i2 = idx - 2496;
            int ts = i2 >> 6, c = i2 & 63;
            w31s[i2] = W0[ts * 80 * 64 + 31 * 64 + c] * 0.0625f;
            w63s[i2] = W0[ts * 80 * 64 + 63 * 64 + c] * 0.0625f;
        } else if (idx < 3456) {                      // zero D (3*1024 floats)
            int i4 = idx - 2688;
            *(float4*)&D[i4 * 4] = make_float4(0.f, 0.f, 0.f, 0.f);
        }
    }
}

// ---------------- main pair kernel: grid dim3(32, 64) ----------------
__global__ __launch_bounds__(256, 8) void epn_main_kernel(
    const float* __restrict__ e, const float* __restrict__ mask,
    const float* __restrict__ Pb, const float* __restrict__ Qb,     // per-t
    const uint2v* __restrict__ fragW0e,  // [4][64]
    const uint4*  __restrict__ fragW1,   // [8][64]
    const float* __restrict__ b1s, const float* __restrict__ w2s,   // per-t
    const float* __restrict__ w31s, const float* __restrict__ w63s, // per-t
    const float* __restrict__ qin, const float* __restrict__ Dp0,
    const float* __restrict__ Dp1, float* __restrict__ Dout, int tstep)
{
    __shared__ float sPi[16][68], sQi[16][68];   // i-side, staged once
    __shared__ float sPj[16][68], sQj[16][68];   // j-side, re-staged once
    __shared__ float sb1[64], sw2[64];

    const int tid  = threadIdx.x;
    const int lane = tid & 63;
    const int wv   = tid >> 6;
    const int nl   = lane & 15;
    const int qd   = lane >> 4;
    const int i0   = blockIdx.y * 16;    // 64 i-tiles
    const int jb   = blockIdx.x * 32;    // 32 j-blocks, 2 j-tiles each
    const int sr   = tid >> 4, sc4 = (tid & 15) * 4;

    // qa = q + sum of prior timestep deltas (uniform branches on tstep)
    float qi = qin[i0 + sr], qj = qin[jb + sr];
    if (tstep > 0) { qi += Dp0[i0 + sr]; qj += Dp0[jb + sr]; }
    if (tstep > 1) { qi += Dp1[i0 + sr]; qj += Dp1[jb + sr]; }
    {
        f32x4 w31v = *(const f32x4*)&w31s[sc4];
        f32x4 w63v = *(const f32x4*)&w63s[sc4];
        f32x4 pbi = *(const f32x4*)&Pb[(i0 + sr) * 64 + sc4];
        f32x4 qbi = *(const f32x4*)&Qb[(i0 + sr) * 64 + sc4];
        f32x4 pbj = *(const f32x4*)&Pb[(jb + sr) * 64 + sc4];
        f32x4 qbj = *(const f32x4*)&Qb[(jb + sr) * 64 + sc4];
        *(f32x4*)&sPi[sr][sc4] = pbi + qi * w31v;
        *(f32x4*)&sQi[sr][sc4] = qbi + qi * w63v;
        *(f32x4*)&sPj[sr][sc4] = pbj + qj * w31v;
        *(f32x4*)&sQj[sr][sc4] = qbj + qj * w63v;
    }
    if (tid < 64) { sb1[tid] = b1s[tid]; sw2[tid] = w2s[tid]; }

    // weight frags in registers
    uint2v Aw0e[4];
    #pragma unroll
    for (int t = 0; t < 4; ++t) Aw0e[t] = fragW0e[t * 64 + lane];
    uint4 w1r[8];
    #pragma unroll
    for (int i = 0; i < 8; ++i) w1r[i] = fragW1[i * 64 + lane];

    // e/mask prefetch for gs=0
    float4 eP = *(const float4*)(e + ((size_t)(i0 + wv * 4) * Nn + (jb + nl)) * 16 + qd * 4);
    float  mP = mask[(size_t)(i0 + wv * 4) * Nn + jb + nl];

    __syncthreads();

    for (int st = 0; st < 2; ++st) {
        // precompute next j-tile staged values (loads land during compute)
        f32x4 pjn, qjn;
        if (st == 0) {
            int jatom = jb + 16 + sr;
            float qn = qin[jatom];
            if (tstep > 0) qn += Dp0[jatom];
            if (tstep > 1) qn += Dp1[jatom];
            f32x4 w31v = *(const f32x4*)&w31s[sc4];
            f32x4 w63v = *(const f32x4*)&w63s[sc4];
            f32x4 pbj = *(const f32x4*)&Pb[jatom * 64 + sc4];
            f32x4 qbj = *(const f32x4*)&Qb[jatom * 64 + sc4];
            pjn = pbj + qn * w31v;
            qjn = qbj + qn * w63v;
        }

        #pragma unroll
        for (int g = 0; g < 4; ++g) {
            const int il = wv * 4 + g;
            float4 ec = eP; float mc = mP;
            const int gs = st * 4 + g;
            if (gs < 7) {   // prefetch next (step, group)
                int ngs = gs + 1, nst = ngs >> 2, ng = ngs & 3;
                int nil = wv * 4 + ng;
                eP = *(const float4*)(e + ((size_t)(i0 + nil) * Nn + (jb + nst * 16 + nl)) * 16 + qd * 4);
                mP = mask[(size_t)(i0 + nil) * Nn + jb + nst * 16 + nl];
            }

            uint2v ep = {pkrtz(ec.x, ec.y), pkrtz(ec.z, ec.w)};
            half4 Be = __builtin_bit_cast(half4, ep);

            // layer 1 (C-init = Pi+Qj / Pj+Qi) -> relu -> pack into L2 B-frags
            uint4v bu[2], bv[2];
            #pragma unroll
            for (int t = 0; t < 4; ++t) {
                const int off = t * 16 + qd * 4;
                f32x4 Pi = *(const f32x4*)&sPi[il][off];    // wave-uniform broadcast
                f32x4 Qi = *(const f32x4*)&sQi[il][off];
                f32x4 Qj = *(const f32x4*)&sQj[nl][off];    // per-lane
                f32x4 Pj = *(const f32x4*)&sPj[nl][off];
                half4 aw = __builtin_bit_cast(half4, Aw0e[t]);
                f32x4 Eu = max0(mfma16(aw, Be, Pi + Qj));
                f32x4 Ev = max0(mfma16(aw, Be, Pj + Qi));
                const int sp = t & 1, b = (t >> 1) * 2;
                bu[sp][b]     = pkrtz(Eu[0], Eu[1]);
                bu[sp][b + 1] = pkrtz(Eu[2], Eu[3]);
                bv[sp][b]     = pkrtz(Ev[0], Ev[1]);
                bv[sp][b + 1] = pkrtz(Ev[2], Ev[3]);
            }

            // layer 2 (C-init = b1/16) + epilogue (16x folded into w2s)
            f32x4 s4 = {0.f, 0.f, 0.f, 0.f};
            #pragma unroll
            for (int t2 = 0; t2 < 4; ++t2) {
                f32x4 binit = *(const f32x4*)&sb1[t2 * 16 + qd * 4];
                f32x4 w2q   = *(const f32x4*)&sw2[t2 * 16 + qd * 4];
                half8 w1a = __builtin_bit_cast(half8, w1r[t2]);
                half8 w1b = __builtin_bit_cast(half8, w1r[4 + t2]);
                f32x4 x = MFMAH32(w1a, __builtin_bit_cast(half8, bu[0]), binit);
                x = MFMAH32(w1b, __builtin_bit_cast(half8, bu[1]), x);
                f32x4 y = MFMAH32(w1a, __builtin_bit_cast(half8, bv[0]), binit);
                y = MFMAH32(w1b, __builtin_bit_cast(half8, bv[1]), y);
                s4 += (max0(x) - max0(y)) * w2q;
            }

            float s = ((s4[0] + s4[1]) + (s4[2] + s4[3])) * mc;
            s += __shfl_xor(s, 1);
            s += __shfl_xor(s, 2);
            s += __shfl_xor(s, 4);
            s += __shfl_xor(s, 8);
            s += __shfl_xor(s, 16);
            s += __shfl_xor(s, 32);
            if (lane == 0) atomicAdd(&Dout[i0 + il], s);
        }

        if (st == 0) {   // swap in next j-tile
            __syncthreads();
            *(f32x4*)&sPj[sr][sc4] = pjn;
            *(f32x4*)&sQj[sr][sc4] = qjn;
            __syncthreads();
        }
    }
}

// ---------------- final: qout = q + D0 + D1 + D2 ----------------
__global__ __launch_bounds__(256) void epn_final_kernel(
    const float* __restrict__ qin, const float* __restrict__ D,
    float* __restrict__ qout)
{
    int i = blockIdx.x * 256 + threadIdx.x;
    qout[i] = qin[i] + D[i] + D[Nn + i] + D[2 * Nn + i];
}

extern "C" void kernel_launch(void* const* d_in, const int* in_sizes, int n_in,
                              void* d_out, int out_size, void* d_ws, size_t ws_size,
                              hipStream_t stream) {
    const float* h    = (const float*)d_in[0];
    const float* e    = (const float*)d_in[1];
    const float* q    = (const float*)d_in[2];
    const float* mask = (const float*)d_in[3];
    const float* W0   = (const float*)d_in[5];
    const float* b0   = (const float*)d_in[6];
    const float* W1   = (const float*)d_in[7];
    const float* b1   = (const float*)d_in[8];
    const float* W2   = (const float*)d_in[9];
    // d_in[10] = b2 cancels in the antisymmetrization

    float* qout = (float*)d_out;
    char*  ws   = (char*)d_ws;
    float*  Pb   = (float*)(ws);                         // 768 KB
    float*  Qb   = (float*)(ws + 786432);                // 768 KB
    uint2v* fw0e = (uint2v*)(ws + 1572864);              // 6 KB
    uint4*  fw1  = (uint4*)(ws + 1579008);               // 24 KB
    float*  b1s  = (float*)(ws + 1603584);               // 768 B
    float*  w2s  = (float*)(ws + 1604352);               // 768 B
    float*  w31s = (float*)(ws + 1605120);               // 768 B
    float*  w63s = (float*)(ws + 1605888);               // 768 B
    float*  D    = (float*)(ws + 1606656);               // 12 KB

    epn_setup_kernel<<<782, 256, 0, stream>>>(W0, W1, b0, b1, W2, h,
                                              fw0e, fw1, b1s, w2s, w31s, w63s,
                                              Pb, Qb, D);
    for (int t = 0; t < 3; ++t) {
        epn_main_kernel<<<dim3(32, 64), 256, 0, stream>>>(
            e, mask, Pb + (size_t)t * Nn * 64, Qb + (size_t)t * Nn * 64,
            fw0e + (size_t)t * 4 * 64, fw1 + (size_t)t * 8 * 64,
            b1s + t * 64, w2s + t * 64, w31s + t * 64, w63s + t * 64,
            q, D, D + Nn, D + (size_t)t * Nn, t);
    }
    epn_final_kernel<<<4, 256, 0, stream>>>(q, D, qout);
}